// Round 8
// baseline (281.045 us; speedup 1.0000x reference)
//
#include <hip/hip_runtime.h>

// Problem constants
#define TT 2000
#define NN 64
#define CC 512
#define SS 200
#define NP 1000          // timestep pairs in the compacted stream
#define PF 8             // fallback prefetch depth
#define LN2 0.69314718055994530942f

// ---------------- workspace layout (bytes) ----------------
#define OFF_PLAB 0ull
#define SZ_PLAB  ((unsigned long long)NN * NP * 64 * 16)          // 65,536,000
#define OFF_PB   (OFF_PLAB + SZ_PLAB)
#define SZ_PB    ((unsigned long long)NN * NP * 8)                // 512,000
#define OFF_TPAD (OFF_PB + SZ_PB)
#define SZ_TPAD  ((unsigned long long)NN * 256 * 4)               // 65,536
#define OFF_LOSS (OFF_TPAD + SZ_TPAD)
#define SZ_LOSS  (NN * 4)
#define WS_NEED  (OFF_LOSS + SZ_LOSS)

__device__ __forceinline__ unsigned bf16rne(float x) {
    unsigned b = __float_as_uint(x);
    return (b + 0x7FFFu + ((b >> 16) & 1u)) >> 16;      // round-to-nearest-even
}

// lane l <- lane l-1 (lane 0 <- 0), single VALU op (v_mov_b32_dpp wave_shr:1)
__device__ __forceinline__ float dpp_shr1(float x) {
    return __int_as_float(__builtin_amdgcn_update_dpp(
        0, __float_as_int(x), 0x138 /*WAVE_SHR1*/, 0xF, 0xF, true));
}

// ---- kernel 0: clamped column table tpad[n][j] = targets[n][min(j,199)] ----
__global__ void ctc_tpad(const int* __restrict__ targets, int* __restrict__ tpad)
{
    int n = blockIdx.x, j = threadIdx.x;
    tpad[n * 256 + j] = targets[n * SS + (j < SS ? j : SS - 1)];
}

// ---- kernel 1: compaction, pair-interleaved. grid=(NP,16) x 64 threads. ----
__global__ __launch_bounds__(64, 1)
void ctc_compact(const float* __restrict__ lp,
                 const int*  __restrict__ tpad,
                 const int*  __restrict__ tgt_len,
                 uint4*      __restrict__ plab4,
                 float2*     __restrict__ pbP)
{
    const int p  = blockIdx.x;
    const int l  = threadIdx.x;
    const int j  = 4 * l;
    const int ta = 2 * p + 1;
    const int tb = (2 * p + 2 < TT) ? (2 * p + 2) : (TT - 1);

    #pragma unroll
    for (int k = 0; k < 4; ++k) {
        const int n = blockIdx.y * 4 + k;
        const float* rowa = lp + ((size_t)ta * NN + n) * CC;
        const float* rowb = lp + ((size_t)tb * NN + n) * CC;
        const int4 c  = *(const int4*)(tpad + n * 256 + j);
        const int  tl = tgt_len[n];
        float a0 = (j + 0 < tl) ? __expf(rowa[c.x]) : 0.f;
        float a1 = (j + 1 < tl) ? __expf(rowa[c.y]) : 0.f;
        float a2 = (j + 2 < tl) ? __expf(rowa[c.z]) : 0.f;
        float a3 = (j + 3 < tl) ? __expf(rowa[c.w]) : 0.f;
        float b0 = (j + 0 < tl) ? __expf(rowb[c.x]) : 0.f;
        float b1 = (j + 1 < tl) ? __expf(rowb[c.y]) : 0.f;
        float b2 = (j + 2 < tl) ? __expf(rowb[c.z]) : 0.f;
        float b3 = (j + 3 < tl) ? __expf(rowb[c.w]) : 0.f;
        uint4 w;
        w.x = bf16rne(a0) | (bf16rne(a1) << 16);
        w.y = bf16rne(a2) | (bf16rne(a3) << 16);
        w.z = bf16rne(b0) | (bf16rne(b1) << 16);
        w.w = bf16rne(b2) | (bf16rne(b3) << 16);
        plab4[((size_t)n * NP + p) * 64 + l] = w;
        if (l == 0)
            pbP[(size_t)n * NP + p] = make_float2(__expf(rowa[0]), __expf(rowb[0]));
    }
}

// ---- kernel 2: serial scan. One wave per n; lane l owns states 8l..8l+7.
// Linear domain, per-lane power-of-2 block floating point. Cross-lane p7 via
// DPP wave_shr:1 (1 VALU op vs ~120cy ds_bpermute round trip). Frame scale
// sc7e hoisted to 8-step boundaries; boundary does 2-hop adoption (frontier
// moves 2 states/step -> can cross TWO lanes per block; triple-crossing needs
// >=9 steps, impossible) + a dd>64 rescue so conversion is always exact.
__global__ __launch_bounds__(64, 1)
void ctc_scan(const float*  __restrict__ lp,
              const uint4*  __restrict__ plab4,
              const float2* __restrict__ pbP,
              const int*    __restrict__ targets,
              const int*    __restrict__ in_len,
              const int*    __restrict__ tgt_len,
              float*        __restrict__ loss_ws)
{
    const int n = blockIdx.x;
    const int l = threadIdx.x;

    __shared__ float dumpS[512];
    __shared__ float lmArr[64];

    const int tl = tgt_len[n];

    float allowm[4];
    #pragma unroll
    for (int q = 0; q < 4; ++q) {
        int pos  = 4 * l + q;
        int posc = pos < SS ? pos : SS - 1;
        int pp   = pos - 1 < 0 ? 0 : (pos - 1 < SS ? pos - 1 : SS - 1);
        allowm[q] = (pos >= 1 && targets[n * SS + posc] != targets[n * SS + pp])
                    ? 1.0f : 0.0f;
    }
    const float me0 = (4*l+0 <= tl) ? 1.f : 0.f;
    const float me1 = (4*l+1 <= tl) ? 1.f : 0.f;
    const float me2 = (4*l+2 <= tl) ? 1.f : 0.f;
    const float me3 = (4*l+3 <= tl) ? 1.f : 0.f;

    const int inlen = in_len[n];
    const uint4*  pw  = plab4 + (size_t)n * NP * 64 + l;
    const float2* pfn = pbP   + (size_t)n * NP;

    float S0=0.f,S1=0.f,S2=0.f,S3=0.f,S4=0.f,S5=0.f,S6=0.f,S7=0.f;
    if (l == 0) {
        const float* row0 = lp + (size_t)n * CC;
        S0 = __expf(row0[0]);                    // state 0: blank
        S1 = __expf(row0[targets[n * SS]]);      // state 1: first label
    }
    float logM    = 0.0f;
    bool  activeB = (l == 0);
    float sc7e;

    uint4  WA = pw[0*64], WB = pw[1*64], WC = pw[2*64], WD = pw[3*64];
    float2 FA = pfn[0],   FB = pfn[1],   FC = pfn[2],   FD = pfn[3];

    int p = 0, t = 1;

// Boundary (every 8 steps): propagate frames to the (up to 2) lanes the
// frontier can reach this block, then fix the conversion constant sc7e.
#define BOUNDARY do {                                                         \
    float pm1 = dpp_shr1(logM);                                               \
    if (!activeB) logM = pm1;              /* hop 1 */                        \
    float pm2 = dpp_shr1(logM);                                               \
    if (!activeB) logM = pm2;              /* hop 2 (double-crossing) */      \
    float pmF = dpp_shr1(logM);            /* sender's FINAL frame */         \
    float dd  = pmF - logM;                                                   \
    if (l > 0 && activeB && dd > 64.0f) {  /* receiver far below sender:   */ \
        int di = (int)dd;                  /* adopt frame, rescale own down */ \
        int dA = di > 126 ? 126 : di;                                         \
        float sA = __uint_as_float((unsigned)(127 - dA) << 23);               \
        int dB = di - dA; dB = dB > 126 ? 126 : dB;                           \
        float sB = __uint_as_float((unsigned)(127 - dB) << 23);               \
        float st = sA * sB;                                                   \
        S0*=st;S1*=st;S2*=st;S3*=st;S4*=st;S5*=st;S6*=st;S7*=st;              \
        logM = pmF; dd = 0.0f;                                                \
    }                                                                         \
    float ddc = fminf(fmaxf(dd, -126.0f), 64.0f);                             \
    sc7e = (l == 0) ? 0.0f                                                    \
         : __uint_as_float((unsigned)((int)ddc + 127) << 23);   /* 2^ddc */   \
} while (0)

#define ONESTEP(wlo, whi, pbv, FRZ) do {                                      \
    float q0 = __uint_as_float((wlo) << 16);                                  \
    float q1 = __uint_as_float((wlo) & 0xFFFF0000u);                          \
    float q2 = __uint_as_float((whi) << 16);                                  \
    float q3 = __uint_as_float((whi) & 0xFFFF0000u);                          \
    float pb = (pbv);                                                         \
    float p7 = dpp_shr1(S7) * sc7e;       /* lane0: dpp=0 and sc7e=0 */       \
    float n7=(S7+S6+allowm[3]*S5)*q3;                                         \
    float n6=(S6+S5)*pb*me3;                                                  \
    float n5=(S5+S4+allowm[2]*S3)*q2;                                         \
    float n4=(S4+S3)*pb*me2;                                                  \
    float n3=(S3+S2+allowm[1]*S1)*q1;                                         \
    float n2=(S2+S1)*pb*me1;                                                  \
    float n1=(S1+S0+allowm[0]*p7)*q0;                                         \
    float n0=(S0+p7)*pb*me0;                                                  \
    if (FRZ) {                                                                \
        bool upd = t < inlen;                                                 \
        S7=upd?n7:S7; S6=upd?n6:S6; S5=upd?n5:S5; S4=upd?n4:S4;               \
        S3=upd?n3:S3; S2=upd?n2:S2; S1=upd?n1:S1; S0=upd?n0:S0;               \
    } else {                                                                  \
        S7=n7; S6=n6; S5=n5; S4=n4; S3=n3; S2=n2; S1=n1; S0=n0;               \
    }                                                                         \
    ++t;                                                                      \
} while (0)

#define PAIRF(Wv, Fv, FRZ, REFILL) do {                                       \
    ONESTEP(Wv.x, Wv.y, Fv.x, FRZ);                                           \
    ONESTEP(Wv.z, Wv.w, Fv.y, FRZ);                                           \
    if (REFILL) {                                                             \
        int pr_ = p + 4; pr_ = pr_ < NP ? pr_ : NP - 1;                       \
        Wv = pw[(size_t)pr_ * 64];                                            \
        Fv = pfn[pr_];                                                        \
    }                                                                         \
    ++p;                                                                      \
} while (0)

#define RENORM do {                                                           \
    float mx = fmaxf(fmaxf(fmaxf(S0,S1),fmaxf(S2,S3)),                        \
                     fmaxf(fmaxf(S4,S5),fmaxf(S6,S7)));                       \
    int e = (mx > 0.0f) ? ((int)(__float_as_uint(mx) >> 23) - 127) : 0;       \
    float sc = __uint_as_float((unsigned)(127 - e) << 23);   /* 2^-e */       \
    logM += (float)e;                                                         \
    S0*=sc;S1*=sc;S2*=sc;S3*=sc;S4*=sc;S5*=sc;S6*=sc;S7*=sc;                  \
    activeB = mx > 0.0f;                                                      \
} while (0)

    BOUNDARY;

    if (inlen >= TT) {          // fast path (this dataset: input_lengths == T)
        for (int b = 0; b < 249; ++b) {
            PAIRF(WA,FA,0,1); PAIRF(WB,FB,0,1);
            PAIRF(WC,FC,0,1); PAIRF(WD,FD,0,1);
            RENORM; BOUNDARY;
        }
        PAIRF(WA,FA,0,0); PAIRF(WB,FB,0,0); PAIRF(WC,FC,0,0);
        ONESTEP(WD.x, WD.y, FD.x, 0);          // t = 1999
    } else {                    // general path with per-step freeze
        for (int b = 0; b < 249; ++b) {
            PAIRF(WA,FA,1,1); PAIRF(WB,FB,1,1);
            PAIRF(WC,FC,1,1); PAIRF(WD,FD,1,1);
            RENORM; BOUNDARY;
        }
        PAIRF(WA,FA,1,0); PAIRF(WB,FB,1,0); PAIRF(WC,FC,1,0);
        ONESTEP(WD.x, WD.y, FD.x, 1);
    }

#undef BOUNDARY
#undef ONESTEP
#undef PAIRF
#undef RENORM

    // ---- epilogue ----
    __syncthreads();
    dumpS[8*l+0]=S0; dumpS[8*l+1]=S1; dumpS[8*l+2]=S2; dumpS[8*l+3]=S3;
    dumpS[8*l+4]=S4; dumpS[8*l+5]=S5; dumpS[8*l+6]=S6; dumpS[8*l+7]=S7;
    lmArr[l] = logM;
    __syncthreads();
    if (l == 0) {
        int sA = 2 * tl - 1, sB = 2 * tl;
        float a  = dumpS[sA];
        float b  = dumpS[sB];
        float la = __logf(a) + lmArr[sA >> 3] * LN2;
        float lb = __logf(b) + lmArr[sB >> 3] * LN2;
        float m  = fmaxf(la, lb);
        float loss = -(m + __logf(__expf(la - m) + __expf(lb - m)));
        loss_ws[n] = loss / (float)tl;
    }
}

// ---------------- fallback: round-5 single-kernel scan (proven) ------------
#define NCr (NN*CC)
__global__ __launch_bounds__(64, 1)
void ctc_alpha_fb(const float* __restrict__ lp, const int* __restrict__ targets,
                  const int* __restrict__ in_len, const int* __restrict__ tgt_len,
                  float* __restrict__ loss_ws)
{
    const int n = blockIdx.x;
    const int l = threadIdx.x;
    __shared__ float dumpS[512];
    __shared__ float lmArr[64];
    const int tl   = tgt_len[n];
    const int smax = 2 * tl;
    int   cls[4];
    float allowm[4];
    #pragma unroll
    for (int q = 0; q < 4; ++q) {
        int s    = 8 * l + 2 * q + 1;
        int pos  = (s - 1) >> 1;
        int posc = pos < SS ? pos : SS - 1;
        int c    = targets[n * SS + posc];
        int pp   = pos - 1 < 0 ? 0 : (pos - 1 < SS ? pos - 1 : SS - 1);
        int cp   = targets[n * SS + pp];
        cls[q]    = c;
        allowm[q] = (pos >= 1 && c != cp) ? 1.0f : 0.0f;
    }
    float m0=(8*l+0<=smax)?1.f:0.f, m1=(8*l+1<=smax)?1.f:0.f;
    float m2=(8*l+2<=smax)?1.f:0.f, m3=(8*l+3<=smax)?1.f:0.f;
    float m4=(8*l+4<=smax)?1.f:0.f, m5=(8*l+5<=smax)?1.f:0.f;
    float m6=(8*l+6<=smax)?1.f:0.f, m7=(8*l+7<=smax)?1.f:0.f;
    const int inlen = in_len[n];
    const float* base = lp + (size_t)n * CC;
    float S0=0.f,S1=0.f,S2=0.f,S3=0.f,S4=0.f,S5=0.f,S6=0.f,S7=0.f;
    bool active = (l == 0);
    if (l == 0) { S0 = __expf(base[0]); S1 = __expf(base[cls[0]]); }
    float logM = 0.0f;
    float Gb[PF], G0[PF], G1[PF], G2[PF], G3[PF];
    #pragma unroll
    for (int u = 0; u < PF; ++u) {
        const float* r = base + (size_t)(1 + u) * NCr;
        Gb[u]=r[0]; G0[u]=r[cls[0]]; G1[u]=r[cls[1]]; G2[u]=r[cls[2]]; G3[u]=r[cls[3]];
    }
    int t = 1;
#define STEPF(u) do {                                                         \
    float pb=__expf(Gb[u]), q0=__expf(G0[u]), q1=__expf(G1[u]),               \
          q2=__expf(G2[u]), q3=__expf(G3[u]);                                 \
    int rowpf = (t + PF < TT) ? (t + PF) : (TT - 1);                          \
    const float* r_ = base + (size_t)rowpf * NCr;                             \
    Gb[u]=r_[0]; G0[u]=r_[cls[0]]; G1[u]=r_[cls[1]];                          \
    G2[u]=r_[cls[2]]; G3[u]=r_[cls[3]];                                       \
    float p7 = __shfl_up(S7, 1);                                              \
    float fm = __shfl_up(logM, 1);                                            \
    if (l == 0) p7 = 0.0f;                                                    \
    if (!active && p7 > 0.0f) { logM = fm; active = true; }                   \
    float dd = fminf(fmaxf(fm - logM, -126.0f), 127.0f);                      \
    p7 *= __uint_as_float((unsigned)((int)dd + 127) << 23);                   \
    float n7=(S7+S6+allowm[3]*S5)*q3*m7;                                      \
    float n6=(S6+S5)*pb*m6;                                                   \
    float n5=(S5+S4+allowm[2]*S3)*q2*m5;                                      \
    float n4=(S4+S3)*pb*m4;                                                   \
    float n3=(S3+S2+allowm[1]*S1)*q1*m3;                                      \
    float n2=(S2+S1)*pb*m2;                                                   \
    float n1=(S1+S0+allowm[0]*p7)*q0*m1;                                      \
    float n0=(S0+p7)*pb*m0;                                                   \
    bool upd = t < inlen;                                                     \
    S7=upd?n7:S7; S6=upd?n6:S6; S5=upd?n5:S5; S4=upd?n4:S4;                   \
    S3=upd?n3:S3; S2=upd?n2:S2; S1=upd?n1:S1; S0=upd?n0:S0;                   \
    ++t;                                                                      \
} while (0)
#define RENORMF do {                                                          \
    float mx = fmaxf(fmaxf(fmaxf(S0,S1),fmaxf(S2,S3)),                        \
                     fmaxf(fmaxf(S4,S5),fmaxf(S6,S7)));                       \
    int e = (mx > 0.0f) ? ((int)(__float_as_uint(mx) >> 23) - 127) : 0;       \
    float sc = __uint_as_float((unsigned)(127 - e) << 23);                    \
    logM += (float)e;                                                         \
    S0*=sc;S1*=sc;S2*=sc;S3*=sc;S4*=sc;S5*=sc;S6*=sc;S7*=sc;                  \
} while (0)
    for (int tb = 0; tb < 249; ++tb) {
        STEPF(0); STEPF(1); STEPF(2); STEPF(3);
        STEPF(4); STEPF(5); STEPF(6); STEPF(7);
        RENORMF;
    }
    STEPF(0); STEPF(1); STEPF(2); STEPF(3); STEPF(4); STEPF(5); STEPF(6);
#undef STEPF
#undef RENORMF
    __syncthreads();
    dumpS[8*l+0]=S0; dumpS[8*l+1]=S1; dumpS[8*l+2]=S2; dumpS[8*l+3]=S3;
    dumpS[8*l+4]=S4; dumpS[8*l+5]=S5; dumpS[8*l+6]=S6; dumpS[8*l+7]=S7;
    lmArr[l] = logM;
    __syncthreads();
    if (l == 0) {
        int sA = 2 * tl - 1, sB = 2 * tl;
        float a  = dumpS[sA];
        float b  = dumpS[sB];
        float la = __logf(a) + lmArr[sA >> 3] * LN2;
        float lb = __logf(b) + lmArr[sB >> 3] * LN2;
        float m  = fmaxf(la, lb);
        float loss = -(m + __logf(__expf(la - m) + __expf(lb - m)));
        loss_ws[n] = loss / (float)tl;
    }
}

__global__ void ctc_reduce(const float* __restrict__ loss_ws, float* __restrict__ out)
{
    float v = loss_ws[threadIdx.x];
    #pragma unroll
    for (int off = 32; off > 0; off >>= 1)
        v += __shfl_down(v, off);
    if (threadIdx.x == 0)
        out[0] = v / (float)NN;
}

extern "C" void kernel_launch(void* const* d_in, const int* in_sizes, int n_in,
                              void* d_out, int out_size, void* d_ws, size_t ws_size,
                              hipStream_t stream)
{
    const float* lp      = (const float*)d_in[0];
    const int*   targets = (const int*)d_in[1];
    const int*   in_len  = (const int*)d_in[2];
    const int*   tgt_len = (const int*)d_in[3];
    float*       out     = (float*)d_out;
    char*        ws      = (char*)d_ws;

    if (ws_size >= WS_NEED) {
        uint4*  plab4  = (uint4*)(ws + OFF_PLAB);
        float2* pbP    = (float2*)(ws + OFF_PB);
        int*    tpad   = (int*)(ws + OFF_TPAD);
        float*  lossws = (float*)(ws + OFF_LOSS);
        hipLaunchKernelGGL(ctc_tpad,    dim3(NN), dim3(256), 0, stream, targets, tpad);
        hipLaunchKernelGGL(ctc_compact, dim3(NP, 16), dim3(64), 0, stream,
                           lp, tpad, tgt_len, plab4, pbP);
        hipLaunchKernelGGL(ctc_scan,    dim3(NN), dim3(64),  0, stream,
                           lp, plab4, pbP, targets, in_len, tgt_len, lossws);
        hipLaunchKernelGGL(ctc_reduce,  dim3(1),  dim3(64),  0, stream, lossws, out);
    } else {
        float* lossws = (float*)ws;   // only 256 B needed
        hipLaunchKernelGGL(ctc_alpha_fb, dim3(NN), dim3(64), 0, stream,
                           lp, targets, in_len, tgt_len, lossws);
        hipLaunchKernelGGL(ctc_reduce,   dim3(1),  dim3(64), 0, stream, lossws, out);
    }
}

// Round 9
// 240.805 us; speedup vs baseline: 1.1671x; 1.1671x over previous
//
#include <hip/hip_runtime.h>

// Problem constants
#define TT 2000
#define NN 64
#define CC 512
#define SS 200
#define NP 1000          // timestep pairs in the compacted stream
#define PF 8             // fallback prefetch depth
#define LN2 0.69314718055994530942f

// ---------------- workspace layout (bytes) ----------------
#define OFF_PLAB 0ull
#define SZ_PLAB  ((unsigned long long)NN * NP * 64 * 16)          // 65,536,000
#define OFF_PB   (OFF_PLAB + SZ_PLAB)
#define SZ_PB    ((unsigned long long)NN * NP * 8)                // 512,000
#define OFF_TPAD (OFF_PB + SZ_PB)
#define SZ_TPAD  ((unsigned long long)NN * 256 * 4)               // 65,536
#define OFF_LOSS (OFF_TPAD + SZ_TPAD)
#define SZ_LOSS  (NN * 4)
#define WS_NEED  (OFF_LOSS + SZ_LOSS)

__device__ __forceinline__ unsigned bf16rne(float x) {
    unsigned b = __float_as_uint(x);
    return (b + 0x7FFFu + ((b >> 16) & 1u)) >> 16;      // round-to-nearest-even
}

// lane l <- lane l-1 (lane 0 <- 0), single VALU op (v_mov_b32_dpp wave_shr:1)
__device__ __forceinline__ float dpp_shr1(float x) {
    return __int_as_float(__builtin_amdgcn_update_dpp(
        0, __float_as_int(x), 0x138 /*WAVE_SHR1*/, 0xF, 0xF, true));
}

// ---- kernel 0: clamped column table tpad[n][j] = targets[n][min(j,199)] ----
__global__ void ctc_tpad(const int* __restrict__ targets, int* __restrict__ tpad)
{
    int n = blockIdx.x, j = threadIdx.x;
    tpad[n * 256 + j] = targets[n * SS + (j < SS ? j : SS - 1)];
}

// ---- kernel 1: compaction, pair-interleaved. grid=(NP,16) x 64 threads. ----
__global__ __launch_bounds__(64, 1)
void ctc_compact(const float* __restrict__ lp,
                 const int*  __restrict__ tpad,
                 const int*  __restrict__ tgt_len,
                 uint4*      __restrict__ plab4,
                 float2*     __restrict__ pbP)
{
    const int p  = blockIdx.x;
    const int l  = threadIdx.x;
    const int j  = 4 * l;
    const int ta = 2 * p + 1;
    const int tb = (2 * p + 2 < TT) ? (2 * p + 2) : (TT - 1);

    #pragma unroll
    for (int k = 0; k < 4; ++k) {
        const int n = blockIdx.y * 4 + k;
        const float* rowa = lp + ((size_t)ta * NN + n) * CC;
        const float* rowb = lp + ((size_t)tb * NN + n) * CC;
        const int4 c  = *(const int4*)(tpad + n * 256 + j);
        const int  tl = tgt_len[n];
        float a0 = (j + 0 < tl) ? __expf(rowa[c.x]) : 0.f;
        float a1 = (j + 1 < tl) ? __expf(rowa[c.y]) : 0.f;
        float a2 = (j + 2 < tl) ? __expf(rowa[c.z]) : 0.f;
        float a3 = (j + 3 < tl) ? __expf(rowa[c.w]) : 0.f;
        float b0 = (j + 0 < tl) ? __expf(rowb[c.x]) : 0.f;
        float b1 = (j + 1 < tl) ? __expf(rowb[c.y]) : 0.f;
        float b2 = (j + 2 < tl) ? __expf(rowb[c.z]) : 0.f;
        float b3 = (j + 3 < tl) ? __expf(rowb[c.w]) : 0.f;
        uint4 w;
        w.x = bf16rne(a0) | (bf16rne(a1) << 16);
        w.y = bf16rne(a2) | (bf16rne(a3) << 16);
        w.z = bf16rne(b0) | (bf16rne(b1) << 16);
        w.w = bf16rne(b2) | (bf16rne(b3) << 16);
        plab4[((size_t)n * NP + p) * 64 + l] = w;
        if (l == 0)
            pbP[(size_t)n * NP + p] = make_float2(__expf(rowa[0]), __expf(rowb[0]));
    }
}

// ---- kernel 2: serial scan. One wave per n; lane l owns states 8l..8l+7.
// Linear domain, per-lane power-of-2 block floating point, DPP cross-lane.
// This round: even-state validity masks REMOVED from the hot loop (states
// above 2*tl are garbage that never flows downward into the readout; their
// magnitude tracks valid states so the per-lane renorm window and logM stay
// exact) and the pair pipeline deepened to 8 slots (16-step lookahead).
__global__ __launch_bounds__(64, 1)
void ctc_scan(const float*  __restrict__ lp,
              const uint4*  __restrict__ plab4,
              const float2* __restrict__ pbP,
              const int*    __restrict__ targets,
              const int*    __restrict__ in_len,
              const int*    __restrict__ tgt_len,
              float*        __restrict__ loss_ws)
{
    const int n = blockIdx.x;
    const int l = threadIdx.x;

    __shared__ float dumpS[512];
    __shared__ float lmArr[64];

    const int tl = tgt_len[n];

    float allowm[4];
    #pragma unroll
    for (int q = 0; q < 4; ++q) {
        int pos  = 4 * l + q;
        int posc = pos < SS ? pos : SS - 1;
        int pp   = pos - 1 < 0 ? 0 : (pos - 1 < SS ? pos - 1 : SS - 1);
        allowm[q] = (pos >= 1 && targets[n * SS + posc] != targets[n * SS + pp])
                    ? 1.0f : 0.0f;
    }

    const int inlen = in_len[n];
    const uint4*  pw  = plab4 + (size_t)n * NP * 64 + l;
    const float2* pfn = pbP   + (size_t)n * NP;

    float S0=0.f,S1=0.f,S2=0.f,S3=0.f,S4=0.f,S5=0.f,S6=0.f,S7=0.f;
    if (l == 0) {
        const float* row0 = lp + (size_t)n * CC;
        S0 = __expf(row0[0]);                    // state 0: blank
        S1 = __expf(row0[targets[n * SS]]);      // state 1: first label
    }
    float logM    = 0.0f;
    bool  activeB = (l == 0);
    float sc7e;

    // 8-slot pipeline: pairs 0..7 preloaded (16 timesteps of lookahead)
    uint4  WA = pw[0*64], WB = pw[1*64], WC = pw[2*64], WD = pw[3*64];
    uint4  WE = pw[4*64], WF = pw[5*64], WG = pw[6*64], WH = pw[7*64];
    float2 FA = pfn[0],   FB = pfn[1],   FC = pfn[2],   FD = pfn[3];
    float2 FE = pfn[4],   FF = pfn[5],   FG = pfn[6],   FH = pfn[7];

    int p = 0, t = 1;

// Boundary (every 8 steps): 2 adoption hops (frontier moves <=2 lanes per
// 8-step block) + final-frame shfl + dd>64 exact rescue. Proven absmax 0.0.
#define BOUNDARY do {                                                         \
    float pm1 = dpp_shr1(logM);                                               \
    if (!activeB) logM = pm1;              /* hop 1 */                        \
    float pm2 = dpp_shr1(logM);                                               \
    if (!activeB) logM = pm2;              /* hop 2 (double-crossing) */      \
    float pmF = dpp_shr1(logM);            /* sender's FINAL frame */         \
    float dd  = pmF - logM;                                                   \
    if (l > 0 && activeB && dd > 64.0f) {                                     \
        int di = (int)dd;                                                     \
        int dA = di > 126 ? 126 : di;                                         \
        float sA = __uint_as_float((unsigned)(127 - dA) << 23);               \
        int dB = di - dA; dB = dB > 126 ? 126 : dB;                           \
        float sB = __uint_as_float((unsigned)(127 - dB) << 23);               \
        float st = sA * sB;                                                   \
        S0*=st;S1*=st;S2*=st;S3*=st;S4*=st;S5*=st;S6*=st;S7*=st;              \
        logM = pmF; dd = 0.0f;                                                \
    }                                                                         \
    float ddc = fminf(fmaxf(dd, -126.0f), 64.0f);                             \
    sc7e = (l == 0) ? 0.0f                                                    \
         : __uint_as_float((unsigned)((int)ddc + 127) << 23);   /* 2^ddc */   \
} while (0)

// One timestep, no validity masks: 4 unpack + 2 (p7) + 4x(add,fma,mul) odd
// + 4x(add,mul) even = 26 VALU.
#define ONESTEP(wlo, whi, pbv) do {                                           \
    float q0 = __uint_as_float((wlo) << 16);                                  \
    float q1 = __uint_as_float((wlo) & 0xFFFF0000u);                          \
    float q2 = __uint_as_float((whi) << 16);                                  \
    float q3 = __uint_as_float((whi) & 0xFFFF0000u);                          \
    float pb = (pbv);                                                         \
    float p7 = dpp_shr1(S7) * sc7e;       /* lane0: dpp=0 and sc7e=0 */       \
    float n7=(S7+S6+allowm[3]*S5)*q3;                                         \
    float n6=(S6+S5)*pb;                                                      \
    float n5=(S5+S4+allowm[2]*S3)*q2;                                         \
    float n4=(S4+S3)*pb;                                                      \
    float n3=(S3+S2+allowm[1]*S1)*q1;                                         \
    float n2=(S2+S1)*pb;                                                      \
    float n1=(S1+S0+allowm[0]*p7)*q0;                                         \
    float n0=(S0+p7)*pb;                                                      \
    S7=n7; S6=n6; S5=n5; S4=n4; S3=n3; S2=n2; S1=n1; S0=n0;                   \
    ++t;                                                                      \
} while (0)

#define PAIRF(Wv, Fv, REFILL) do {                                            \
    ONESTEP(Wv.x, Wv.y, Fv.x);                                                \
    ONESTEP(Wv.z, Wv.w, Fv.y);                                                \
    if (REFILL) {                                                             \
        int pr_ = p + 8; pr_ = pr_ < NP ? pr_ : NP - 1;                       \
        Wv = pw[(size_t)pr_ * 64];                                            \
        Fv = pfn[pr_];                                                        \
    }                                                                         \
    ++p;                                                                      \
} while (0)

#define RENORM do {                                                           \
    float mx = fmaxf(fmaxf(fmaxf(S0,S1),fmaxf(S2,S3)),                        \
                     fmaxf(fmaxf(S4,S5),fmaxf(S6,S7)));                       \
    int e = (mx > 0.0f) ? ((int)(__float_as_uint(mx) >> 23) - 127) : 0;       \
    float sc = __uint_as_float((unsigned)(127 - e) << 23);   /* 2^-e */       \
    logM += (float)e;                                                         \
    S0*=sc;S1*=sc;S2*=sc;S3*=sc;S4*=sc;S5*=sc;S6*=sc;S7*=sc;                  \
    activeB = mx > 0.0f;                                                      \
} while (0)

    BOUNDARY;

    if (inlen >= TT) {          // fast path (this dataset: input_lengths == T)
        // 124 x 16 steps (two 8-step half-blocks) + 8 + 7 tail = 1999
        for (int b = 0; b < 124; ++b) {
            PAIRF(WA,FA,1); PAIRF(WB,FB,1); PAIRF(WC,FC,1); PAIRF(WD,FD,1);
            RENORM; BOUNDARY;
            PAIRF(WE,FE,1); PAIRF(WF,FF,1); PAIRF(WG,FG,1); PAIRF(WH,FH,1);
            RENORM; BOUNDARY;
        }
        PAIRF(WA,FA,0); PAIRF(WB,FB,0); PAIRF(WC,FC,0); PAIRF(WD,FD,0);
        RENORM; BOUNDARY;
        // tail: slots E..H hold pairs 996..999
        PAIRF(WE,FE,0); PAIRF(WF,FF,0); PAIRF(WG,FG,0);
        ONESTEP(WH.x, WH.y, FH.x);              // t = 1999
    } else {
        // general path: freeze past inlen (unused for this dataset).
        // Uses the same 8-slot stream but checks t<inlen per step via selects.
        for (int b = 0; b < 124; ++b) {
            #define GP(Wv,Fv) do {                                            \
                float oS0=S0,oS1=S1,oS2=S2,oS3=S3,oS4=S4,oS5=S5,oS6=S6,oS7=S7;\
                bool u1 = t < inlen; ONESTEP(Wv.x, Wv.y, Fv.x);               \
                if (!u1){S0=oS0;S1=oS1;S2=oS2;S3=oS3;S4=oS4;S5=oS5;S6=oS6;S7=oS7;}\
                float pS0=S0,pS1=S1,pS2=S2,pS3=S3,pS4=S4,pS5=S5,pS6=S6,pS7=S7;\
                bool u2 = t < inlen; ONESTEP(Wv.z, Wv.w, Fv.y);               \
                if (!u2){S0=pS0;S1=pS1;S2=pS2;S3=pS3;S4=pS4;S5=pS5;S6=pS6;S7=pS7;}\
                int pr_ = p + 8; pr_ = pr_ < NP ? pr_ : NP - 1;               \
                Wv = pw[(size_t)pr_ * 64]; Fv = pfn[pr_]; ++p;                \
            } while (0)
            GP(WA,FA); GP(WB,FB); GP(WC,FC); GP(WD,FD);
            RENORM; BOUNDARY;
            GP(WE,FE); GP(WF,FF); GP(WG,FG); GP(WH,FH);
            RENORM; BOUNDARY;
        }
        GP(WA,FA); GP(WB,FB); GP(WC,FC); GP(WD,FD);
        RENORM; BOUNDARY;
        GP(WE,FE); GP(WF,FF); GP(WG,FG);
        {
            float oS0=S0,oS1=S1,oS2=S2,oS3=S3,oS4=S4,oS5=S5,oS6=S6,oS7=S7;
            bool u1 = t < inlen; ONESTEP(WH.x, WH.y, FH.x);
            if (!u1){S0=oS0;S1=oS1;S2=oS2;S3=oS3;S4=oS4;S5=oS5;S6=oS6;S7=oS7;}
        }
            #undef GP
    }

#undef BOUNDARY
#undef ONESTEP
#undef PAIRF
#undef RENORM

    // ---- epilogue ----
    __syncthreads();
    dumpS[8*l+0]=S0; dumpS[8*l+1]=S1; dumpS[8*l+2]=S2; dumpS[8*l+3]=S3;
    dumpS[8*l+4]=S4; dumpS[8*l+5]=S5; dumpS[8*l+6]=S6; dumpS[8*l+7]=S7;
    lmArr[l] = logM;
    __syncthreads();
    if (l == 0) {
        int sA = 2 * tl - 1, sB = 2 * tl;
        float a  = dumpS[sA];
        float b  = dumpS[sB];
        float la = __logf(a) + lmArr[sA >> 3] * LN2;
        float lb = __logf(b) + lmArr[sB >> 3] * LN2;
        float m  = fmaxf(la, lb);
        float loss = -(m + __logf(__expf(la - m) + __expf(lb - m)));
        loss_ws[n] = loss / (float)tl;
    }
}

// ---------------- fallback: round-5 single-kernel scan (proven) ------------
#define NCr (NN*CC)
__global__ __launch_bounds__(64, 1)
void ctc_alpha_fb(const float* __restrict__ lp, const int* __restrict__ targets,
                  const int* __restrict__ in_len, const int* __restrict__ tgt_len,
                  float* __restrict__ loss_ws)
{
    const int n = blockIdx.x;
    const int l = threadIdx.x;
    __shared__ float dumpS[512];
    __shared__ float lmArr[64];
    const int tl   = tgt_len[n];
    const int smax = 2 * tl;
    int   cls[4];
    float allowm[4];
    #pragma unroll
    for (int q = 0; q < 4; ++q) {
        int s    = 8 * l + 2 * q + 1;
        int pos  = (s - 1) >> 1;
        int posc = pos < SS ? pos : SS - 1;
        int c    = targets[n * SS + posc];
        int pp   = pos - 1 < 0 ? 0 : (pos - 1 < SS ? pos - 1 : SS - 1);
        int cp   = targets[n * SS + pp];
        cls[q]    = c;
        allowm[q] = (pos >= 1 && c != cp) ? 1.0f : 0.0f;
    }
    float m0=(8*l+0<=smax)?1.f:0.f, m1=(8*l+1<=smax)?1.f:0.f;
    float m2=(8*l+2<=smax)?1.f:0.f, m3=(8*l+3<=smax)?1.f:0.f;
    float m4=(8*l+4<=smax)?1.f:0.f, m5=(8*l+5<=smax)?1.f:0.f;
    float m6=(8*l+6<=smax)?1.f:0.f, m7=(8*l+7<=smax)?1.f:0.f;
    const int inlen = in_len[n];
    const float* base = lp + (size_t)n * CC;
    float S0=0.f,S1=0.f,S2=0.f,S3=0.f,S4=0.f,S5=0.f,S6=0.f,S7=0.f;
    bool active = (l == 0);
    if (l == 0) { S0 = __expf(base[0]); S1 = __expf(base[cls[0]]); }
    float logM = 0.0f;
    float Gb[PF], G0[PF], G1[PF], G2[PF], G3[PF];
    #pragma unroll
    for (int u = 0; u < PF; ++u) {
        const float* r = base + (size_t)(1 + u) * NCr;
        Gb[u]=r[0]; G0[u]=r[cls[0]]; G1[u]=r[cls[1]]; G2[u]=r[cls[2]]; G3[u]=r[cls[3]];
    }
    int t = 1;
#define STEPF(u) do {                                                         \
    float pb=__expf(Gb[u]), q0=__expf(G0[u]), q1=__expf(G1[u]),               \
          q2=__expf(G2[u]), q3=__expf(G3[u]);                                 \
    int rowpf = (t + PF < TT) ? (t + PF) : (TT - 1);                          \
    const float* r_ = base + (size_t)rowpf * NCr;                             \
    Gb[u]=r_[0]; G0[u]=r_[cls[0]]; G1[u]=r_[cls[1]];                          \
    G2[u]=r_[cls[2]]; G3[u]=r_[cls[3]];                                       \
    float p7 = __shfl_up(S7, 1);                                              \
    float fm = __shfl_up(logM, 1);                                            \
    if (l == 0) p7 = 0.0f;                                                    \
    if (!active && p7 > 0.0f) { logM = fm; active = true; }                   \
    float dd = fminf(fmaxf(fm - logM, -126.0f), 127.0f);                      \
    p7 *= __uint_as_float((unsigned)((int)dd + 127) << 23);                   \
    float n7=(S7+S6+allowm[3]*S5)*q3*m7;                                      \
    float n6=(S6+S5)*pb*m6;                                                   \
    float n5=(S5+S4+allowm[2]*S3)*q2*m5;                                      \
    float n4=(S4+S3)*pb*m4;                                                   \
    float n3=(S3+S2+allowm[1]*S1)*q1*m3;                                      \
    float n2=(S2+S1)*pb*m2;                                                   \
    float n1=(S1+S0+allowm[0]*p7)*q0*m1;                                      \
    float n0=(S0+p7)*pb*m0;                                                   \
    bool upd = t < inlen;                                                     \
    S7=upd?n7:S7; S6=upd?n6:S6; S5=upd?n5:S5; S4=upd?n4:S4;                   \
    S3=upd?n3:S3; S2=upd?n2:S2; S1=upd?n1:S1; S0=upd?n0:S0;                   \
    ++t;                                                                      \
} while (0)
#define RENORMF do {                                                          \
    float mx = fmaxf(fmaxf(fmaxf(S0,S1),fmaxf(S2,S3)),                        \
                     fmaxf(fmaxf(S4,S5),fmaxf(S6,S7)));                       \
    int e = (mx > 0.0f) ? ((int)(__float_as_uint(mx) >> 23) - 127) : 0;       \
    float sc = __uint_as_float((unsigned)(127 - e) << 23);                    \
    logM += (float)e;                                                         \
    S0*=sc;S1*=sc;S2*=sc;S3*=sc;S4*=sc;S5*=sc;S6*=sc;S7*=sc;                  \
} while (0)
    for (int tb = 0; tb < 249; ++tb) {
        STEPF(0); STEPF(1); STEPF(2); STEPF(3);
        STEPF(4); STEPF(5); STEPF(6); STEPF(7);
        RENORMF;
    }
    STEPF(0); STEPF(1); STEPF(2); STEPF(3); STEPF(4); STEPF(5); STEPF(6);
#undef STEPF
#undef RENORMF
    __syncthreads();
    dumpS[8*l+0]=S0; dumpS[8*l+1]=S1; dumpS[8*l+2]=S2; dumpS[8*l+3]=S3;
    dumpS[8*l+4]=S4; dumpS[8*l+5]=S5; dumpS[8*l+6]=S6; dumpS[8*l+7]=S7;
    lmArr[l] = logM;
    __syncthreads();
    if (l == 0) {
        int sA = 2 * tl - 1, sB = 2 * tl;
        float a  = dumpS[sA];
        float b  = dumpS[sB];
        float la = __logf(a) + lmArr[sA >> 3] * LN2;
        float lb = __logf(b) + lmArr[sB >> 3] * LN2;
        float m  = fmaxf(la, lb);
        float loss = -(m + __logf(__expf(la - m) + __expf(lb - m)));
        loss_ws[n] = loss / (float)tl;
    }
}

__global__ void ctc_reduce(const float* __restrict__ loss_ws, float* __restrict__ out)
{
    float v = loss_ws[threadIdx.x];
    #pragma unroll
    for (int off = 32; off > 0; off >>= 1)
        v += __shfl_down(v, off);
    if (threadIdx.x == 0)
        out[0] = v / (float)NN;
}

extern "C" void kernel_launch(void* const* d_in, const int* in_sizes, int n_in,
                              void* d_out, int out_size, void* d_ws, size_t ws_size,
                              hipStream_t stream)
{
    const float* lp      = (const float*)d_in[0];
    const int*   targets = (const int*)d_in[1];
    const int*   in_len  = (const int*)d_in[2];
    const int*   tgt_len = (const int*)d_in[3];
    float*       out     = (float*)d_out;
    char*        ws      = (char*)d_ws;

    if (ws_size >= WS_NEED) {
        uint4*  plab4  = (uint4*)(ws + OFF_PLAB);
        float2* pbP    = (float2*)(ws + OFF_PB);
        int*    tpad   = (int*)(ws + OFF_TPAD);
        float*  lossws = (float*)(ws + OFF_LOSS);
        hipLaunchKernelGGL(ctc_tpad,    dim3(NN), dim3(256), 0, stream, targets, tpad);
        hipLaunchKernelGGL(ctc_compact, dim3(NP, 16), dim3(64), 0, stream,
                           lp, tpad, tgt_len, plab4, pbP);
        hipLaunchKernelGGL(ctc_scan,    dim3(NN), dim3(64),  0, stream,
                           lp, plab4, pbP, targets, in_len, tgt_len, lossws);
        hipLaunchKernelGGL(ctc_reduce,  dim3(1),  dim3(64),  0, stream, lossws, out);
    } else {
        float* lossws = (float*)ws;   // only 256 B needed
        hipLaunchKernelGGL(ctc_alpha_fb, dim3(NN), dim3(64), 0, stream,
                           lp, targets, in_len, tgt_len, lossws);
        hipLaunchKernelGGL(ctc_reduce,   dim3(1),  dim3(64), 0, stream, lossws, out);
    }
}

// Round 11
// 217.812 us; speedup vs baseline: 1.2903x; 1.1056x over previous
//
#include <hip/hip_runtime.h>

// Problem constants
#define TT 2000
#define NN 64
#define CC 512
#define SS 200
#define NP 1000          // timestep pairs in the compacted stream
#define PF 8             // fallback prefetch depth
#define LN2 0.69314718055994530942f

// ---------------- workspace layout (bytes) ----------------
#define OFF_PLAB 0ull
#define SZ_PLAB  ((unsigned long long)NN * NP * 64 * 16)          // 65,536,000
#define OFF_PB   (OFF_PLAB + SZ_PLAB)
#define SZ_PB    ((unsigned long long)NN * NP * 8)                // 512,000
#define OFF_TPAD (OFF_PB + SZ_PB)
#define SZ_TPAD  ((unsigned long long)NN * 256 * 4)               // 65,536
#define OFF_LOSS (OFF_TPAD + SZ_TPAD)
#define SZ_LOSS  (NN * 4)
#define WS_NEED  (OFF_LOSS + SZ_LOSS)

__device__ __forceinline__ unsigned bf16rne(float x) {
    unsigned b = __float_as_uint(x);
    return (b + 0x7FFFu + ((b >> 16) & 1u)) >> 16;      // round-to-nearest-even
}

// lane l <- lane l-1 (lane 0 <- 0), single VALU op (v_mov_b32_dpp wave_shr:1)
__device__ __forceinline__ float dpp_shr1(float x) {
    return __int_as_float(__builtin_amdgcn_update_dpp(
        0, __float_as_int(x), 0x138 /*WAVE_SHR1*/, 0xF, 0xF, true));
}
__device__ __forceinline__ int dpp_shr1_i(int x) {
    return __builtin_amdgcn_update_dpp(0, x, 0x138, 0xF, 0xF, true);
}

// ---- kernel 0: clamped column table tpad[n][j] = targets[n][min(j,199)] ----
__global__ void ctc_tpad(const int* __restrict__ targets, int* __restrict__ tpad)
{
    int n = blockIdx.x, j = threadIdx.x;
    tpad[n * 256 + j] = targets[n * SS + (j < SS ? j : SS - 1)];
}

// ---- kernel 1: compaction. grid=(NP,16) x 64 threads. Pair p = (2p+1,2p+2).
// Pack for the 4-wave scan: each uint holds ONE label position L at TWO
// timesteps: lo bf16 = q(ta), hi bf16 = q(tb). uint index ((n*NP)+p)*256 + L.
__global__ __launch_bounds__(64, 1)
void ctc_compact(const float* __restrict__ lp,
                 const int*  __restrict__ tpad,
                 const int*  __restrict__ tgt_len,
                 uint4*      __restrict__ plab4,
                 float2*     __restrict__ pbP)
{
    const int p  = blockIdx.x;
    const int l  = threadIdx.x;
    const int j  = 4 * l;
    const int ta = 2 * p + 1;
    const int tb = (2 * p + 2 < TT) ? (2 * p + 2) : (TT - 1);

    #pragma unroll
    for (int k = 0; k < 4; ++k) {
        const int n = blockIdx.y * 4 + k;
        const float* rowa = lp + ((size_t)ta * NN + n) * CC;
        const float* rowb = lp + ((size_t)tb * NN + n) * CC;
        const int4 c  = *(const int4*)(tpad + n * 256 + j);
        const int  tl = tgt_len[n];
        float a0 = (j + 0 < tl) ? __expf(rowa[c.x]) : 0.f;
        float a1 = (j + 1 < tl) ? __expf(rowa[c.y]) : 0.f;
        float a2 = (j + 2 < tl) ? __expf(rowa[c.z]) : 0.f;
        float a3 = (j + 3 < tl) ? __expf(rowa[c.w]) : 0.f;
        float b0 = (j + 0 < tl) ? __expf(rowb[c.x]) : 0.f;
        float b1 = (j + 1 < tl) ? __expf(rowb[c.y]) : 0.f;
        float b2 = (j + 2 < tl) ? __expf(rowb[c.z]) : 0.f;
        float b3 = (j + 3 < tl) ? __expf(rowb[c.w]) : 0.f;
        uint4 w;
        w.x = bf16rne(a0) | (bf16rne(b0) << 16);   // L=4l
        w.y = bf16rne(a1) | (bf16rne(b1) << 16);   // L=4l+1
        w.z = bf16rne(a2) | (bf16rne(b2) << 16);   // L=4l+2
        w.w = bf16rne(a3) | (bf16rne(b3) << 16);   // L=4l+3
        plab4[((size_t)n * NP + p) * 64 + l] = w;
        if (l == 0)
            pbP[(size_t)n * NP + p] = make_float2(__expf(rowa[0]), __expf(rowb[0]));
    }
}

// =================== 4-wave pipelined scan ===================
// Block = 256 threads = 4 waves; wave w owns states 128w..128w+127, lane l
// owns (even 2L, odd 2L+1) with L = 64w+l. Lattice flow is strictly upward
// in s, so wave w trails wave w-1, receiving the per-step boundary value
// (state 128w-1) through a full-T LDS ring. Per-lane power-of-2 frames;
// ballot-broadcast frame adoption; spin-sync on LDS progress counters.
// ROUND-11 FIX: scE1/scER (the scale factors ONESTEP4 actually multiplies
// by) are now refreshed with sc7e every block for ALL waves; previously the
// refresh lived inside CONSQ-only CONS_SCE, leaving wave 0's scales frozen
// at 1.0 -> unscaled cross-lane transfers after the first renorm (abs 7.5).

#define SPIN(tg_) do {                                                        \
    while (__hip_atomic_load(progc, __ATOMIC_ACQUIRE,                         \
                             __HIP_MEMORY_SCOPE_WORKGROUP) < (tg_)) {}        \
} while (0)

#define CONS_ADOPT(lmB_) do {                                                 \
    if (lane0) {                                                              \
        if (!active) logM = (lmB_);                                           \
        else { int dB_ = (lmB_) - logM;                                       \
               if (dB_ > 100) { S0 = 0.f; S1 = 0.f; logM = (lmB_); } }        \
    }                                                                         \
} while (0)

#define CONS_SCE(lmA_, lmB_, E1_, ER_) do {                                   \
    int dA_ = (lmA_) - logM; int dB_ = (lmB_) - logM;                         \
    dA_ = dA_ < -126 ? -126 : (dA_ > 126 ? 126 : dA_);                        \
    dB_ = dB_ < -126 ? -126 : (dB_ > 126 ? 126 : dB_);                        \
    float sA_ = __uint_as_float((unsigned)(dA_ + 127) << 23);                 \
    float sB_ = __uint_as_float((unsigned)(dB_ + 127) << 23);                 \
    if (lane0) { (E1_) = sA_; (ER_) = sB_; }                                  \
} while (0)

#define ONESTEP4(Wb, HALF, PBV, RV, SCE) do {                                 \
    float q_ = (HALF) ? __uint_as_float((Wb) & 0xFFFF0000u)                   \
                      : __uint_as_float((Wb) << 16);                          \
    float pin_ = dpp_shr1(S1);                                                \
    if constexpr (CONSQ) pin_ = lane0 ? (RV) : pin_;                          \
    float pe_ = pin_ * (SCE);                                                 \
    float n1_ = (S1 + S0 + allow * pe_) * q_;                                 \
    float n0_ = (S0 + pe_) * (PBV);                                           \
    if constexpr (FRZQ) { bool u_ = t < inlen;                                \
        S1 = u_ ? n1_ : S1; S0 = u_ ? n0_ : S0; }                             \
    else { S1 = n1_; S0 = n0_; }                                              \
    if constexpr (PRODQ) { *prodPtr = S1; prodPtr += prodInc; }               \
    ++t;                                                                      \
} while (0)

#define PAIRX(Wv, Fv, R0, R1, SE0, SE1, REFILL) do {                          \
    ONESTEP4(Wv, 0, Fv.x, R0, SE0);                                           \
    ONESTEP4(Wv, 1, Fv.y, R1, SE1);                                           \
    if (REFILL) { int pr_ = p + 8; if (pr_ > NP - 1) pr_ = NP - 1;            \
        Wv = plabU[baseE + ((unsigned)pr_ << 8)]; Fv = pfn[pr_]; }            \
    ++p;                                                                      \
} while (0)

#define RENORM4 do {                                                          \
    float mx_ = fmaxf(S0, S1);                                                \
    active = mx_ > 0.0f;                                                      \
    int e_ = (int)(__float_as_uint(mx_) >> 23) - 127;                         \
    float sc_ = __uint_as_float((unsigned)(127 - e_) << 23);                  \
    logM += e_; S0 *= sc_; S1 *= sc_;                                         \
} while (0)

#define BOUNDARY4 do {                                                        \
    unsigned long long mk_ = __ballot(active);                                \
    int idx_ = mk_ ? (63 - __builtin_clzll(mk_)) : 0;                         \
    int bc_ = __builtin_amdgcn_readlane(logM, idx_);                          \
    if (!active) logM = bc_;                                                  \
    int pmF_ = dpp_shr1_i(logM);                                              \
    int dd_ = pmF_ - logM;                                                    \
    if (l != 0 && active && dd_ > 100) {                                      \
        S0 = 0.f; S1 = 0.f; logM = pmF_; dd_ = 0; active = false;             \
    }                                                                         \
    dd_ = dd_ < -126 ? -126 : (dd_ > 126 ? 126 : dd_);                        \
    sc7e = __uint_as_float((unsigned)(dd_ + 127) << 23);                      \
} while (0)

// U = set used this block (a/b); Lo = set preloaded for next block
#define BLOCK8(WsA,FsA,WsB,FsB,WsC,FsC,WsD,FsD, REFILL, U, Lo) do {           \
    int lmA_ = 0, lmB_ = 0;                                                   \
    if constexpr (CONSQ) {                                                    \
        if ((bIdx & 3) == 0) { int tg_ = (bIdx + 6) * 8;                      \
            if (tg_ > 1999) tg_ = 1999; SPIN(tg_); }                          \
        int nb_ = bIdx + 1;                                                   \
        float4 ra_ = *(const float4*)(ringVc + 8 * nb_);                      \
        float4 rb_ = *(const float4*)(ringVc + 8 * nb_ + 4);                  \
        rv_##Lo##0 = ra_.x; rv_##Lo##1 = ra_.y;                               \
        rv_##Lo##2 = ra_.z; rv_##Lo##3 = ra_.w;                               \
        rv_##Lo##4 = rb_.x; rv_##Lo##5 = rb_.y;                               \
        rv_##Lo##6 = rb_.z; rv_##Lo##7 = rb_.w;                               \
        lmA_ = ringLMc[bIdx]; lmB_ = ringLMc[bIdx + 1];                       \
    }                                                                         \
    PAIRX(WsA, FsA, rv_##U##0, rv_##U##1, scE1_##U, scER_##U, REFILL);        \
    PAIRX(WsB, FsB, rv_##U##2, rv_##U##3, scER_##U, scER_##U, REFILL);        \
    PAIRX(WsC, FsC, rv_##U##4, rv_##U##5, scER_##U, scER_##U, REFILL);        \
    PAIRX(WsD, FsD, rv_##U##6, rv_##U##7, scER_##U, scER_##U, REFILL);        \
    RENORM4;                                                                  \
    if constexpr (CONSQ) { CONS_ADOPT(lmB_); }                                \
    BOUNDARY4;                                                                \
    scE1_##Lo = sc7e; scER_##Lo = sc7e;          /* FIX: all waves, all lanes */\
    if constexpr (CONSQ) { CONS_SCE(lmA_, lmB_, scE1_##Lo, scER_##Lo); }      \
    if constexpr (PRODQ) {                                                    \
        if (l == 63) ringLMp[bIdx + 1] = logM;                                \
        if (lane0) __hip_atomic_store(progp, t - 1, __ATOMIC_RELEASE,         \
                                      __HIP_MEMORY_SCOPE_WORKGROUP);          \
    }                                                                         \
    ++bIdx;                                                                   \
} while (0)

template<int PRODQ, int CONSQ, int FRZQ>
__device__ __forceinline__ void scan4_main(
    int l, int inlen, float allow,
    float &S0r, float &S1r, int &logMr, bool activeIn,
    const unsigned* __restrict__ plabU, unsigned baseE,
    const float2* __restrict__ pfn,
    float* prodPtr, int prodInc,
    int* ringLMp, int* progp,
    const float* __restrict__ ringVc, const int* __restrict__ ringLMc,
    int* progc)
{
    float S0 = S0r, S1 = S1r;
    int   logM = logMr;
    bool  active = activeIn;
    float sc7e = 1.0f;
    const bool lane0 = (l == 0);
    int t = 1, p = 0, bIdx = 0;

    // 8-slot pipeline (pairs 0..7 = 16 timesteps lookahead)
    unsigned WA = plabU[baseE +    0u], WB = plabU[baseE +  256u];
    unsigned WC = plabU[baseE +  512u], WD = plabU[baseE +  768u];
    unsigned WE = plabU[baseE + 1024u], WF = plabU[baseE + 1280u];
    unsigned WG = plabU[baseE + 1536u], WH = plabU[baseE + 1792u];
    float2 FA = pfn[0], FB = pfn[1], FC = pfn[2], FD = pfn[3];
    float2 FE = pfn[4], FF = pfn[5], FG = pfn[6], FH = pfn[7];

    // double-buffered ring data + scale factors
    float rv_a0=0.f,rv_a1=0.f,rv_a2=0.f,rv_a3=0.f,rv_a4=0.f,rv_a5=0.f,rv_a6=0.f,rv_a7=0.f;
    float rv_b0=0.f,rv_b1=0.f,rv_b2=0.f,rv_b3=0.f,rv_b4=0.f,rv_b5=0.f,rv_b6=0.f,rv_b7=0.f;
    float scE1_a=1.f, scER_a=1.f, scE1_b=1.f, scER_b=1.f;

    if constexpr (CONSQ) {
        SPIN(48);                                  // covers blocks 0..5
        float4 ra = *(const float4*)(ringVc + 0);
        float4 rb = *(const float4*)(ringVc + 4);
        rv_a0=ra.x; rv_a1=ra.y; rv_a2=ra.z; rv_a3=ra.w;
        rv_a4=rb.x; rv_a5=rb.y; rv_a6=rb.z; rv_a7=rb.w;
        int lmA0 = ringLMc[0], lmB0 = ringLMc[0];
        CONS_ADOPT(lmB0);
        CONS_SCE(lmA0, lmB0, scE1_a, scER_a);
    }

    for (int it = 0; it < 124; ++it) {
        BLOCK8(WA,FA,WB,FB,WC,FC,WD,FD, 1, a, b);
        BLOCK8(WE,FE,WF,FF,WG,FG,WH,FH, 1, b, a);
    }
    // block 248 (t=1985..1992): slots A..D = pairs 992..995; preload tail set b
    BLOCK8(WA,FA,WB,FB,WC,FC,WD,FD, 0, a, b);
    // tail t=1993..1999 (7 steps): slots E..H = pairs 996..999
    ONESTEP4(WE, 0, FE.x, rv_b0, scE1_b);
    ONESTEP4(WE, 1, FE.y, rv_b1, scER_b);
    ONESTEP4(WF, 0, FF.x, rv_b2, scER_b);
    ONESTEP4(WF, 1, FF.y, rv_b3, scER_b);
    ONESTEP4(WG, 0, FG.x, rv_b4, scER_b);
    ONESTEP4(WG, 1, FG.y, rv_b5, scER_b);
    ONESTEP4(WH, 0, FH.x, rv_b6, scER_b);
    if constexpr (PRODQ) {
        if (lane0) __hip_atomic_store(progp, 1999, __ATOMIC_RELEASE,
                                      __HIP_MEMORY_SCOPE_WORKGROUP);
    }

    S0r = S0; S1r = S1; logMr = logM;
}

__global__ __launch_bounds__(256, 1)
void ctc_scan4(const float*  __restrict__ lp,
               const unsigned* __restrict__ plabU,
               const float2* __restrict__ pbP,
               const int*    __restrict__ targets,
               const int*    __restrict__ in_len,
               const int*    __restrict__ tgt_len,
               float*        __restrict__ loss_ws)
{
    const int n   = blockIdx.x;
    const int tid = threadIdx.x;
    const int w   = tid >> 6;
    const int l   = tid & 63;
    const int L   = tid;                 // global state-pair index

    __shared__ __align__(16) float ringV[3][2048];
    __shared__ int   ringLM[3][256];
    __shared__ int   prog[4];
    __shared__ float trash[64];
    __shared__ float aE[256], aO[256];
    __shared__ int   lmS[256];

    if (tid < 3) { prog[tid] = 0; ringLM[tid][0] = 0; ringV[tid][0] = 0.f; }

    const int tl    = tgt_len[n];
    const int inlen = in_len[n];

    // label class + skip-allow for odd state 2L+1 (label position L)
    int posc = L < SS ? L : SS - 1;
    int c    = targets[n * SS + posc];
    int pp   = (L - 1) < 0 ? 0 : ((L - 1) < SS ? L - 1 : SS - 1);
    float allow = (L >= 1 && c != targets[n * SS + pp]) ? 1.f : 0.f;

    float S0 = 0.f, S1 = 0.f;
    bool active = false;
    if (w == 0 && l == 0) {
        const float* row0 = lp + (size_t)n * CC;
        S0 = __expf(row0[0]);            // state 0: blank
        S1 = __expf(row0[c]);            // state 1: first label (c=targets[n][0])
        active = true;
    }
    int logM = 0;

    __syncthreads();                     // LDS init visible to all waves

    const unsigned baseE = (unsigned)(n * NP) * 256u + (unsigned)L;
    const float2*  pfn   = pbP + (size_t)n * NP;

    float* prodPtr = nullptr; int prodInc = 0;
    int *ringLMp = nullptr, *progp = nullptr, *progc = nullptr;
    const float* ringVc = nullptr; const int* ringLMc = nullptr;
    if (w < 3) {
        prodPtr = (l == 63) ? &ringV[w][1] : &trash[l];
        prodInc = (l == 63) ? 1 : 0;
        ringLMp = ringLM[w]; progp = &prog[w];
    }
    if (w > 0) {
        ringVc = ringV[w - 1]; ringLMc = ringLM[w - 1]; progc = &prog[w - 1];
    }

    const bool fastlen = (inlen >= TT);
    if (w == 0) {
        if (fastlen) scan4_main<1,0,0>(l, inlen, allow, S0, S1, logM, active,
                plabU, baseE, pfn, prodPtr, prodInc, ringLMp, progp,
                ringVc, ringLMc, progc);
        else         scan4_main<1,0,1>(l, inlen, allow, S0, S1, logM, active,
                plabU, baseE, pfn, prodPtr, prodInc, ringLMp, progp,
                ringVc, ringLMc, progc);
    } else if (w < 3) {
        if (fastlen) scan4_main<1,1,0>(l, inlen, allow, S0, S1, logM, active,
                plabU, baseE, pfn, prodPtr, prodInc, ringLMp, progp,
                ringVc, ringLMc, progc);
        else         scan4_main<1,1,1>(l, inlen, allow, S0, S1, logM, active,
                plabU, baseE, pfn, prodPtr, prodInc, ringLMp, progp,
                ringVc, ringLMc, progc);
    } else {
        if (fastlen) scan4_main<0,1,0>(l, inlen, allow, S0, S1, logM, active,
                plabU, baseE, pfn, prodPtr, prodInc, ringLMp, progp,
                ringVc, ringLMc, progc);
        else         scan4_main<0,1,1>(l, inlen, allow, S0, S1, logM, active,
                plabU, baseE, pfn, prodPtr, prodInc, ringLMp, progp,
                ringVc, ringLMc, progc);
    }

    // epilogue
    aE[L] = S0; aO[L] = S1; lmS[L] = logM;
    __syncthreads();
    if (tid == 0) {
        int L1 = tl - 1, L2 = tl;        // odd state 2tl-1, even state 2tl
        float la = __logf(aO[L1]) + (float)lmS[L1] * LN2;
        float lb = __logf(aE[L2]) + (float)lmS[L2] * LN2;
        float m  = fmaxf(la, lb);
        float loss = -(m + __logf(__expf(la - m) + __expf(lb - m)));
        loss_ws[n] = loss / (float)tl;
    }
}

#undef SPIN
#undef CONS_ADOPT
#undef CONS_SCE
#undef ONESTEP4
#undef PAIRX
#undef RENORM4
#undef BOUNDARY4
#undef BLOCK8

// ---------------- fallback: round-5 single-kernel scan (proven) ------------
#define NCr (NN*CC)
__global__ __launch_bounds__(64, 1)
void ctc_alpha_fb(const float* __restrict__ lp, const int* __restrict__ targets,
                  const int* __restrict__ in_len, const int* __restrict__ tgt_len,
                  float* __restrict__ loss_ws)
{
    const int n = blockIdx.x;
    const int l = threadIdx.x;
    __shared__ float dumpS[512];
    __shared__ float lmArr[64];
    const int tl   = tgt_len[n];
    const int smax = 2 * tl;
    int   cls[4];
    float allowm[4];
    #pragma unroll
    for (int q = 0; q < 4; ++q) {
        int s    = 8 * l + 2 * q + 1;
        int pos  = (s - 1) >> 1;
        int posc = pos < SS ? pos : SS - 1;
        int c    = targets[n * SS + posc];
        int pp   = pos - 1 < 0 ? 0 : (pos - 1 < SS ? pos - 1 : SS - 1);
        int cp   = targets[n * SS + pp];
        cls[q]    = c;
        allowm[q] = (pos >= 1 && c != cp) ? 1.0f : 0.0f;
    }
    float m0=(8*l+0<=smax)?1.f:0.f, m1=(8*l+1<=smax)?1.f:0.f;
    float m2=(8*l+2<=smax)?1.f:0.f, m3=(8*l+3<=smax)?1.f:0.f;
    float m4=(8*l+4<=smax)?1.f:0.f, m5=(8*l+5<=smax)?1.f:0.f;
    float m6=(8*l+6<=smax)?1.f:0.f, m7=(8*l+7<=smax)?1.f:0.f;
    const int inlen = in_len[n];
    const float* base = lp + (size_t)n * CC;
    float S0=0.f,S1=0.f,S2=0.f,S3=0.f,S4=0.f,S5=0.f,S6=0.f,S7=0.f;
    bool active = (l == 0);
    if (l == 0) { S0 = __expf(base[0]); S1 = __expf(base[cls[0]]); }
    float logM = 0.0f;
    float Gb[PF], G0[PF], G1[PF], G2[PF], G3[PF];
    #pragma unroll
    for (int u = 0; u < PF; ++u) {
        const float* r = base + (size_t)(1 + u) * NCr;
        Gb[u]=r[0]; G0[u]=r[cls[0]]; G1[u]=r[cls[1]]; G2[u]=r[cls[2]]; G3[u]=r[cls[3]];
    }
    int t = 1;
#define STEPF(u) do {                                                         \
    float pb=__expf(Gb[u]), q0=__expf(G0[u]), q1=__expf(G1[u]),               \
          q2=__expf(G2[u]), q3=__expf(G3[u]);                                 \
    int rowpf = (t + PF < TT) ? (t + PF) : (TT - 1);                          \
    const float* r_ = base + (size_t)rowpf * NCr;                             \
    Gb[u]=r_[0]; G0[u]=r_[cls[0]]; G1[u]=r_[cls[1]];                          \
    G2[u]=r_[cls[2]]; G3[u]=r_[cls[3]];                                       \
    float p7 = __shfl_up(S7, 1);                                              \
    float fm = __shfl_up(logM, 1);                                            \
    if (l == 0) p7 = 0.0f;                                                    \
    if (!active && p7 > 0.0f) { logM = fm; active = true; }                   \
    float dd = fminf(fmaxf(fm - logM, -126.0f), 127.0f);                      \
    p7 *= __uint_as_float((unsigned)((int)dd + 127) << 23);                   \
    float n7=(S7+S6+allowm[3]*S5)*q3*m7;                                      \
    float n6=(S6+S5)*pb*m6;                                                   \
    float n5=(S5+S4+allowm[2]*S3)*q2*m5;                                      \
    float n4=(S4+S3)*pb*m4;                                                   \
    float n3=(S3+S2+allowm[1]*S1)*q1*m3;                                      \
    float n2=(S2+S1)*pb*m2;                                                   \
    float n1=(S1+S0+allowm[0]*p7)*q0*m1;                                      \
    float n0=(S0+p7)*pb*m0;                                                   \
    bool upd = t < inlen;                                                     \
    S7=upd?n7:S7; S6=upd?n6:S6; S5=upd?n5:S5; S4=upd?n4:S4;                   \
    S3=upd?n3:S3; S2=upd?n2:S2; S1=upd?n1:S1; S0=upd?n0:S0;                   \
    ++t;                                                                      \
} while (0)
#define RENORMF do {                                                          \
    float mx = fmaxf(fmaxf(fmaxf(S0,S1),fmaxf(S2,S3)),                        \
                     fmaxf(fmaxf(S4,S5),fmaxf(S6,S7)));                       \
    int e = (mx > 0.0f) ? ((int)(__float_as_uint(mx) >> 23) - 127) : 0;       \
    float sc = __uint_as_float((unsigned)(127 - e) << 23);                    \
    logM += (float)e;                                                         \
    S0*=sc;S1*=sc;S2*=sc;S3*=sc;S4*=sc;S5*=sc;S6*=sc;S7*=sc;                  \
} while (0)
    for (int tb = 0; tb < 249; ++tb) {
        STEPF(0); STEPF(1); STEPF(2); STEPF(3);
        STEPF(4); STEPF(5); STEPF(6); STEPF(7);
        RENORMF;
    }
    STEPF(0); STEPF(1); STEPF(2); STEPF(3); STEPF(4); STEPF(5); STEPF(6);
#undef STEPF
#undef RENORMF
    __syncthreads();
    dumpS[8*l+0]=S0; dumpS[8*l+1]=S1; dumpS[8*l+2]=S2; dumpS[8*l+3]=S3;
    dumpS[8*l+4]=S4; dumpS[8*l+5]=S5; dumpS[8*l+6]=S6; dumpS[8*l+7]=S7;
    lmArr[l] = logM;
    __syncthreads();
    if (l == 0) {
        int sA = 2 * tl - 1, sB = 2 * tl;
        float a  = dumpS[sA];
        float b  = dumpS[sB];
        float la = __logf(a) + lmArr[sA >> 3] * LN2;
        float lb = __logf(b) + lmArr[sB >> 3] * LN2;
        float m  = fmaxf(la, lb);
        float loss = -(m + __logf(__expf(la - m) + __expf(lb - m)));
        loss_ws[n] = loss / (float)tl;
    }
}

__global__ void ctc_reduce(const float* __restrict__ loss_ws, float* __restrict__ out)
{
    float v = loss_ws[threadIdx.x];
    #pragma unroll
    for (int off = 32; off > 0; off >>= 1)
        v += __shfl_down(v, off);
    if (threadIdx.x == 0)
        out[0] = v / (float)NN;
}

extern "C" void kernel_launch(void* const* d_in, const int* in_sizes, int n_in,
                              void* d_out, int out_size, void* d_ws, size_t ws_size,
                              hipStream_t stream)
{
    const float* lp      = (const float*)d_in[0];
    const int*   targets = (const int*)d_in[1];
    const int*   in_len  = (const int*)d_in[2];
    const int*   tgt_len = (const int*)d_in[3];
    float*       out     = (float*)d_out;
    char*        ws      = (char*)d_ws;

    if (ws_size >= WS_NEED) {
        uint4*    plab4  = (uint4*)(ws + OFF_PLAB);
        unsigned* plabU  = (unsigned*)(ws + OFF_PLAB);
        float2*   pbP    = (float2*)(ws + OFF_PB);
        int*      tpad   = (int*)(ws + OFF_TPAD);
        float*    lossws = (float*)(ws + OFF_LOSS);
        hipLaunchKernelGGL(ctc_tpad,    dim3(NN), dim3(256), 0, stream, targets, tpad);
        hipLaunchKernelGGL(ctc_compact, dim3(NP, 16), dim3(64), 0, stream,
                           lp, tpad, tgt_len, plab4, pbP);
        hipLaunchKernelGGL(ctc_scan4,   dim3(NN), dim3(256), 0, stream,
                           lp, plabU, pbP, targets, in_len, tgt_len, lossws);
        hipLaunchKernelGGL(ctc_reduce,  dim3(1),  dim3(64),  0, stream, lossws, out);
    } else {
        float* lossws = (float*)ws;   // only 256 B needed
        hipLaunchKernelGGL(ctc_alpha_fb, dim3(NN), dim3(64), 0, stream,
                           lp, targets, in_len, tgt_len, lossws);
        hipLaunchKernelGGL(ctc_reduce,   dim3(1),  dim3(64), 0, stream, lossws, out);
    }
}